// Round 2
// baseline (655.426 us; speedup 1.0000x reference)
//
#include <hip/hip_runtime.h>

// ---------------------------------------------------------------------------
// Pipeline:
//  k_prep : wfc[512,64] -> wfcT[64,512]   (k-major, coalesced in fc k-loop)
//           w2[64,32,3] -> w2t[3,32,64]   (o-contiguous, lane-coalesced)
//  kA     : h[v] = mean_j relu(conv3_j(vp[nb1[v,:]]))               [V]
//  kB     : f1[v,o] = h[v-1]*w1[o,0]+h[v]*w1[o,1]+h[v+1]*w1[o,2]+b1 [V,32]
//  kC     : h2[v,c] = mean_j relu(conv3_j(f1[nb2[v,j],c]))          [V,32]
//  kD     : f2[v,o] = sum_{k,c} h2[v-1+k,c]*w2t[k,c,o] + b2[o]      [V,64]
//  kE     : out[v,:] = softmax(f2[v,:] @ wfcT + bfc)                [V,512]
//
// R2 change: kE __launch_bounds__(128,2). R1 evidence showed VGPR_Count=48
// with an acc[16][4] register tile -> compiler spilled accumulators to
// scratch (WRITE_SIZE 780MB vs 205MB ideal). (128,2) allows 256 VGPR/wave.
// ---------------------------------------------------------------------------

__global__ __launch_bounds__(256) void k_prep(const float* __restrict__ wfc,
                                              const float* __restrict__ w2,
                                              float* __restrict__ wfcT,
                                              float* __restrict__ w2t) {
    int t = blockIdx.x * 256 + threadIdx.x;
    if (t < 512 * 64) {
        // t = k*512 + s  (writes coalesced)
        int k = t >> 9;
        int s = t & 511;
        wfcT[t] = wfc[s * 64 + k];
    } else {
        int i = t - 512 * 64;
        if (i < 64 * 32 * 3) {
            int o = i / 96;
            int r = i - o * 96;
            int c = r / 3;
            int k = r - c * 3;
            w2t[(k * 32 + c) * 64 + o] = w2[i];
        }
    }
}

// conv1 over neighbor axis: one 32-lane segment per vertex
__global__ __launch_bounds__(256) void kA(const float* __restrict__ vp,
                                          const int* __restrict__ nb1,
                                          const float* __restrict__ wv1,
                                          const float* __restrict__ bv1,
                                          float* __restrict__ h, int V) {
    int t = blockIdx.x * 256 + threadIdx.x;
    int v = t >> 5;
    int j = t & 31;
    if (v >= V) return;
    float g = vp[nb1[v * 32 + j]];
    float gm = __shfl_up(g, 1, 32);
    if (j == 0) gm = 0.0f;
    float gp = __shfl_down(g, 1, 32);
    if (j == 31) gp = 0.0f;
    float c = wv1[0] * gm + wv1[1] * g + wv1[2] * gp + bv1[0];
    c = fmaxf(c, 0.0f);
    #pragma unroll
    for (int off = 16; off; off >>= 1) c += __shfl_xor(c, off, 32);
    if (j == 0) h[v] = c * (1.0f / 32.0f);
}

// vertex-shift 3-tap mix into 32 channels
__global__ __launch_bounds__(256) void kB(const float* __restrict__ h,
                                          const float* __restrict__ w1,
                                          const float* __restrict__ b1,
                                          float* __restrict__ f1, int V) {
    int t = blockIdx.x * 256 + threadIdx.x;
    int v = t >> 5;
    int o = t & 31;
    if (v >= V) return;
    float hm = (v > 0) ? h[v - 1] : 0.0f;
    float h0 = h[v];
    float hp = (v + 1 < V) ? h[v + 1] : 0.0f;
    f1[v * 32 + o] = fmaf(hm, w1[o * 3 + 0],
                     fmaf(h0, w1[o * 3 + 1],
                     fmaf(hp, w1[o * 3 + 2], b1[o])));
}

// conv2: gather 32 neighbor rows (32 ch each) into LDS, 3-tap along j, mean
__global__ __launch_bounds__(256) void kC(const float* __restrict__ f1,
                                          const int* __restrict__ nb2,
                                          const float* __restrict__ wv2,
                                          const float* __restrict__ bv2,
                                          float* __restrict__ h2, int V) {
    __shared__ float lds[8 * 32 * 32];  // [vv][j][c], 32 KB
    int t = threadIdx.x;
    int vbase = blockIdx.x * 8;
    int j = t >> 3;        // 0..31
    int seg = t & 7;       // float4 segment within row
    #pragma unroll
    for (int vv = 0; vv < 8; ++vv) {
        int v = vbase + vv;
        float4 val = make_float4(0.f, 0.f, 0.f, 0.f);
        if (v < V) {
            int idx = nb2[v * 32 + j];
            val = *(const float4*)(f1 + (size_t)idx * 32 + seg * 4);
        }
        *(float4*)(lds + vv * 1024 + j * 32 + seg * 4) = val;
    }
    __syncthreads();
    int vv = t >> 5;       // 0..7
    int c = t & 31;
    int v = vbase + vv;
    const float* L = lds + vv * 1024;
    float w0 = wv2[0], w1_ = wv2[1], w2_ = wv2[2], b = bv2[0];
    float prev = 0.0f, cur = L[c];
    float s = 0.0f;
    #pragma unroll
    for (int jj = 0; jj < 32; ++jj) {
        float nxt = (jj < 31) ? L[(jj + 1) * 32 + c] : 0.0f;
        float cv = fmaf(w0, prev, fmaf(w1_, cur, fmaf(w2_, nxt, b)));
        s += fmaxf(cv, 0.0f);
        prev = cur;
        cur = nxt;
    }
    if (v < V) h2[v * 32 + c] = s * (1.0f / 32.0f);
}

// f2 einsum: 64-thread blocks (1 wave), lane = o; h2 indices block-uniform
// (scalar loads), 8 vertices register-blocked so each w2t load feeds 8 FMAs.
__global__ __launch_bounds__(64) void kD(const float* __restrict__ h2,
                                         const float* __restrict__ w2t,
                                         const float* __restrict__ b2,
                                         float* __restrict__ f2, int V) {
    int o = threadIdx.x;
    int v0 = blockIdx.x * 8;
    float bo = b2[o];
    float acc[8];
    #pragma unroll
    for (int m = 0; m < 8; ++m) acc[m] = bo;

    for (int c = 0; c < 32; ++c) {
        float hcol[10];
        #pragma unroll
        for (int r = 0; r < 10; ++r) {
            int vv = v0 - 1 + r;
            hcol[r] = (vv >= 0 && vv < V) ? h2[(size_t)vv * 32 + c] : 0.0f;
        }
        #pragma unroll
        for (int k = 0; k < 3; ++k) {
            float w = w2t[(k * 32 + c) * 64 + o];
            #pragma unroll
            for (int m = 0; m < 8; ++m) acc[m] = fmaf(hcol[m + k], w, acc[m]);
        }
    }
    #pragma unroll
    for (int m = 0; m < 8; ++m) {
        int v = v0 + m;
        if (v < V) f2[(size_t)v * 64 + o] = acc[m];
    }
}

// fc + softmax: 128 threads, 16 vertices/block, thread owns 4 consecutive
// outputs (float4-coalesced wfcT loads), acc[16][4] register tile.
// __launch_bounds__(128, 2): 2 waves/EU min -> up to 256 VGPR/wave, so the
// 64-float accumulator tile stays in registers (R1: 48 VGPR cap spilled it,
// WRITE_SIZE 780MB vs 205MB ideal).
__global__ __launch_bounds__(128, 2) void kE(const float* __restrict__ f2,
                                             const float* __restrict__ wfcT,
                                             const float* __restrict__ bfc,
                                             float* __restrict__ out, int V) {
    __shared__ float f2s[16 * 64];          // 4 KB
    __shared__ float redmax[2][16];
    __shared__ float redsum[2][16];
    int t = threadIdx.x;
    int wid = t >> 6, lane = t & 63;
    int vbase = blockIdx.x * 16;
    int nv = V - vbase; if (nv > 16) nv = 16;

    for (int i = t; i < 256; i += 128) {    // 256 float4 = 16*64 floats
        float4 val = make_float4(0.f, 0.f, 0.f, 0.f);
        if (i < nv * 16) val = ((const float4*)(f2 + (size_t)vbase * 64))[i];
        ((float4*)f2s)[i] = val;
    }
    __syncthreads();

    int s0 = t * 4;
    float4 bv = *(const float4*)(bfc + s0);
    float acc[16][4];
    #pragma unroll
    for (int m = 0; m < 16; ++m) {
        acc[m][0] = bv.x; acc[m][1] = bv.y; acc[m][2] = bv.z; acc[m][3] = bv.w;
    }

    for (int k = 0; k < 64; k += 4) {
        float4 w0 = *(const float4*)(wfcT + (k + 0) * 512 + s0);
        float4 w1 = *(const float4*)(wfcT + (k + 1) * 512 + s0);
        float4 w2 = *(const float4*)(wfcT + (k + 2) * 512 + s0);
        float4 w3 = *(const float4*)(wfcT + (k + 3) * 512 + s0);
        #pragma unroll
        for (int m = 0; m < 16; ++m) {
            float4 f = *(const float4*)(f2s + m * 64 + k);
            acc[m][0] = fmaf(f.x, w0.x, fmaf(f.y, w1.x, fmaf(f.z, w2.x, fmaf(f.w, w3.x, acc[m][0]))));
            acc[m][1] = fmaf(f.x, w0.y, fmaf(f.y, w1.y, fmaf(f.z, w2.y, fmaf(f.w, w3.y, acc[m][1]))));
            acc[m][2] = fmaf(f.x, w0.z, fmaf(f.y, w1.z, fmaf(f.z, w2.z, fmaf(f.w, w3.z, acc[m][2]))));
            acc[m][3] = fmaf(f.x, w0.w, fmaf(f.y, w1.w, fmaf(f.z, w2.w, fmaf(f.w, w3.w, acc[m][3]))));
        }
    }

    // softmax over 512 per vertex: wave-reduce then 2-wave combine via LDS
    #pragma unroll
    for (int m = 0; m < 16; ++m) {
        float lm = fmaxf(fmaxf(acc[m][0], acc[m][1]), fmaxf(acc[m][2], acc[m][3]));
        #pragma unroll
        for (int off = 32; off; off >>= 1) lm = fmaxf(lm, __shfl_xor(lm, off));
        if (lane == 0) redmax[wid][m] = lm;
    }
    __syncthreads();
    #pragma unroll
    for (int m = 0; m < 16; ++m) {
        float gm = fmaxf(redmax[0][m], redmax[1][m]);
        acc[m][0] = __expf(acc[m][0] - gm);
        acc[m][1] = __expf(acc[m][1] - gm);
        acc[m][2] = __expf(acc[m][2] - gm);
        acc[m][3] = __expf(acc[m][3] - gm);
        float ls = (acc[m][0] + acc[m][1]) + (acc[m][2] + acc[m][3]);
        #pragma unroll
        for (int off = 32; off; off >>= 1) ls += __shfl_xor(ls, off);
        if (lane == 0) redsum[wid][m] = ls;
    }
    __syncthreads();
    #pragma unroll
    for (int m = 0; m < 16; ++m) {
        if (m >= nv) break;
        float inv = 1.0f / (redsum[0][m] + redsum[1][m]);
        float4 o4 = make_float4(acc[m][0] * inv, acc[m][1] * inv,
                                acc[m][2] * inv, acc[m][3] * inv);
        *(float4*)(out + (size_t)(vbase + m) * 512 + s0) = o4;
    }
}

extern "C" void kernel_launch(void* const* d_in, const int* in_sizes, int n_in,
                              void* d_out, int out_size, void* d_ws, size_t ws_size,
                              hipStream_t stream) {
    (void)n_in; (void)out_size; (void)ws_size;
    const float* vp  = (const float*)d_in[0];
    const int*   nb1 = (const int*)d_in[1];
    const int*   nb2 = (const int*)d_in[2];
    const float* wv1 = (const float*)d_in[3];
    const float* bv1 = (const float*)d_in[4];
    const float* w1  = (const float*)d_in[5];
    const float* b1  = (const float*)d_in[6];
    const float* wv2 = (const float*)d_in[7];
    const float* bv2 = (const float*)d_in[8];
    const float* w2  = (const float*)d_in[9];
    const float* b2  = (const float*)d_in[10];
    const float* wfc = (const float*)d_in[11];
    const float* bfc = (const float*)d_in[12];
    float* out = (float*)d_out;
    const int V = in_sizes[0];

    float* ws = (float*)d_ws;
    size_t off = 0;
    float* h    = ws + off; off += (size_t)V;
    float* f1   = ws + off; off += (size_t)V * 32;
    float* h2   = ws + off; off += (size_t)V * 32;
    float* f2   = ws + off; off += (size_t)V * 64;
    float* wfcT = ws + off; off += 512 * 64;
    float* w2t  = ws + off; off += 3 * 32 * 64;

    k_prep<<<(512 * 64 + 64 * 32 * 3 + 255) / 256, 256, 0, stream>>>(wfc, w2, wfcT, w2t);
    kA<<<(V * 32 + 255) / 256, 256, 0, stream>>>(vp, nb1, wv1, bv1, h, V);
    kB<<<(V * 32 + 255) / 256, 256, 0, stream>>>(h, w1, b1, f1, V);
    kC<<<(V + 7) / 8, 256, 0, stream>>>(f1, nb2, wv2, bv2, h2, V);
    kD<<<(V + 7) / 8, 64, 0, stream>>>(h2, w2t, b2, f2, V);
    kE<<<(V + 15) / 16, 128, 0, stream>>>(f2, wfcT, bfc, out, V);
}

// Round 3
// 579.182 us; speedup vs baseline: 1.1316x; 1.1316x over previous
//
#include <hip/hip_runtime.h>

// ---------------------------------------------------------------------------
// Pipeline:
//  k_prep : wfc[512,64] -> wfcT[64,512]   (k-major, coalesced in fc k-loop)
//           w2[64,32,3] -> w2t[3,32,64]   (o-contiguous, lane-coalesced)
//  kA     : h[v] = mean_j relu(conv3_j(vp[nb1[v,:]]))               [V]
//  kB     : f1[v,o] = h[v-1]*w1[o,0]+h[v]*w1[o,1]+h[v+1]*w1[o,2]+b1 [V,32]
//  kC     : h2[v,c] = mean_j relu(conv3_j(f1[nb2[v,j],c]))          [V,32]
//  kD     : f2[v,o] = sum_{k,c} h2[v-1+k,c]*w2t[k,c,o] + b2[o]      [V,64]
//  kE     : out[v,:] = softmax(f2[v,:] @ wfcT + bfc)                [V,512]
//
// R3 change: kE accumulator tile as 16 NAMED float4 (macro-expanded), not
// float acc[16][4]. R2 falsified the "RA cap" theory (launch_bounds(128,2)
// left VGPR=48, WRITE=780MB unchanged) -> the alloca was never SROA-promoted;
// scratch traffic (~3.3GB, ~64MB resident > 32MB L2) leaked 575MB writes to
// HBM. Named scalars cannot be scratch unless RA spills (cap=256 here).
// ---------------------------------------------------------------------------

__global__ __launch_bounds__(256) void k_prep(const float* __restrict__ wfc,
                                              const float* __restrict__ w2,
                                              float* __restrict__ wfcT,
                                              float* __restrict__ w2t) {
    int t = blockIdx.x * 256 + threadIdx.x;
    if (t < 512 * 64) {
        int k = t >> 9;
        int s = t & 511;
        wfcT[t] = wfc[s * 64 + k];
    } else {
        int i = t - 512 * 64;
        if (i < 64 * 32 * 3) {
            int o = i / 96;
            int r = i - o * 96;
            int c = r / 3;
            int k = r - c * 3;
            w2t[(k * 32 + c) * 64 + o] = w2[i];
        }
    }
}

// conv1 over neighbor axis: one 32-lane segment per vertex
__global__ __launch_bounds__(256) void kA(const float* __restrict__ vp,
                                          const int* __restrict__ nb1,
                                          const float* __restrict__ wv1,
                                          const float* __restrict__ bv1,
                                          float* __restrict__ h, int V) {
    int t = blockIdx.x * 256 + threadIdx.x;
    int v = t >> 5;
    int j = t & 31;
    if (v >= V) return;
    float g = vp[nb1[v * 32 + j]];
    float gm = __shfl_up(g, 1, 32);
    if (j == 0) gm = 0.0f;
    float gp = __shfl_down(g, 1, 32);
    if (j == 31) gp = 0.0f;
    float c = wv1[0] * gm + wv1[1] * g + wv1[2] * gp + bv1[0];
    c = fmaxf(c, 0.0f);
    #pragma unroll
    for (int off = 16; off; off >>= 1) c += __shfl_xor(c, off, 32);
    if (j == 0) h[v] = c * (1.0f / 32.0f);
}

// vertex-shift 3-tap mix into 32 channels
__global__ __launch_bounds__(256) void kB(const float* __restrict__ h,
                                          const float* __restrict__ w1,
                                          const float* __restrict__ b1,
                                          float* __restrict__ f1, int V) {
    int t = blockIdx.x * 256 + threadIdx.x;
    int v = t >> 5;
    int o = t & 31;
    if (v >= V) return;
    float hm = (v > 0) ? h[v - 1] : 0.0f;
    float h0 = h[v];
    float hp = (v + 1 < V) ? h[v + 1] : 0.0f;
    f1[v * 32 + o] = fmaf(hm, w1[o * 3 + 0],
                     fmaf(h0, w1[o * 3 + 1],
                     fmaf(hp, w1[o * 3 + 2], b1[o])));
}

// conv2: gather 32 neighbor rows (32 ch each) into LDS, 3-tap along j, mean
__global__ __launch_bounds__(256) void kC(const float* __restrict__ f1,
                                          const int* __restrict__ nb2,
                                          const float* __restrict__ wv2,
                                          const float* __restrict__ bv2,
                                          float* __restrict__ h2, int V) {
    __shared__ float lds[8 * 32 * 32];  // [vv][j][c], 32 KB
    int t = threadIdx.x;
    int vbase = blockIdx.x * 8;
    int j = t >> 3;        // 0..31
    int seg = t & 7;       // float4 segment within row
    #pragma unroll
    for (int vv = 0; vv < 8; ++vv) {
        int v = vbase + vv;
        float4 val = make_float4(0.f, 0.f, 0.f, 0.f);
        if (v < V) {
            int idx = nb2[v * 32 + j];
            val = *(const float4*)(f1 + (size_t)idx * 32 + seg * 4);
        }
        *(float4*)(lds + vv * 1024 + j * 32 + seg * 4) = val;
    }
    __syncthreads();
    int vv = t >> 5;       // 0..7
    int c = t & 31;
    int v = vbase + vv;
    const float* L = lds + vv * 1024;
    float w0 = wv2[0], w1_ = wv2[1], w2_ = wv2[2], b = bv2[0];
    float prev = 0.0f, cur = L[c];
    float s = 0.0f;
    #pragma unroll
    for (int jj = 0; jj < 32; ++jj) {
        float nxt = (jj < 31) ? L[(jj + 1) * 32 + c] : 0.0f;
        float cv = fmaf(w0, prev, fmaf(w1_, cur, fmaf(w2_, nxt, b)));
        s += fmaxf(cv, 0.0f);
        prev = cur;
        cur = nxt;
    }
    if (v < V) h2[v * 32 + c] = s * (1.0f / 32.0f);
}

// f2 einsum: 64-thread blocks (1 wave), lane = o; h2 indices block-uniform
// (scalar loads), 8 vertices register-blocked so each w2t load feeds 8 FMAs.
__global__ __launch_bounds__(64) void kD(const float* __restrict__ h2,
                                         const float* __restrict__ w2t,
                                         const float* __restrict__ b2,
                                         float* __restrict__ f2, int V) {
    int o = threadIdx.x;
    int v0 = blockIdx.x * 8;
    float bo = b2[o];
    float acc[8];
    #pragma unroll
    for (int m = 0; m < 8; ++m) acc[m] = bo;

    for (int c = 0; c < 32; ++c) {
        float hcol[10];
        #pragma unroll
        for (int r = 0; r < 10; ++r) {
            int vv = v0 - 1 + r;
            hcol[r] = (vv >= 0 && vv < V) ? h2[(size_t)vv * 32 + c] : 0.0f;
        }
        #pragma unroll
        for (int k = 0; k < 3; ++k) {
            float w = w2t[(k * 32 + c) * 64 + o];
            #pragma unroll
            for (int m = 0; m < 8; ++m) acc[m] = fmaf(hcol[m + k], w, acc[m]);
        }
    }
    #pragma unroll
    for (int m = 0; m < 8; ++m) {
        int v = v0 + m;
        if (v < V) f2[(size_t)v * 64 + o] = acc[m];
    }
}

#define REP16(X) X(0) X(1) X(2) X(3) X(4) X(5) X(6) X(7) \
                 X(8) X(9) X(10) X(11) X(12) X(13) X(14) X(15)

// fc + softmax: 128 threads, 16 vertices/block, thread owns 4 consecutive
// outputs (float4-coalesced wfcT loads). Accumulators are 16 NAMED float4
// registers (macro-expanded) — no alloca, nothing for SROA to miss.
__global__ __launch_bounds__(128, 2) void kE(const float* __restrict__ f2,
                                             const float* __restrict__ wfcT,
                                             const float* __restrict__ bfc,
                                             float* __restrict__ out, int V) {
    __shared__ float f2s[16 * 64];          // 4 KB
    __shared__ float redmax[2][16];
    __shared__ float redsum[2][16];
    int t = threadIdx.x;
    int wid = t >> 6, lane = t & 63;
    int vbase = blockIdx.x * 16;
    int nv = V - vbase; if (nv > 16) nv = 16;

    for (int i = t; i < 256; i += 128) {    // 256 float4 = 16*64 floats
        float4 val = make_float4(0.f, 0.f, 0.f, 0.f);
        if (i < nv * 16) val = ((const float4*)(f2 + (size_t)vbase * 64))[i];
        ((float4*)f2s)[i] = val;
    }
    __syncthreads();

    int s0 = t * 4;
    float4 bv = *(const float4*)(bfc + s0);

#define KE_DECL(m) float4 A##m = bv;
    REP16(KE_DECL)
#undef KE_DECL

    for (int k = 0; k < 64; k += 4) {
        float4 w0 = *(const float4*)(wfcT + (k + 0) * 512 + s0);
        float4 w1 = *(const float4*)(wfcT + (k + 1) * 512 + s0);
        float4 w2 = *(const float4*)(wfcT + (k + 2) * 512 + s0);
        float4 w3 = *(const float4*)(wfcT + (k + 3) * 512 + s0);
#define KE_FMA(m) { \
        float4 f = *(const float4*)(f2s + m * 64 + k); \
        A##m.x = fmaf(f.x, w0.x, fmaf(f.y, w1.x, fmaf(f.z, w2.x, fmaf(f.w, w3.x, A##m.x)))); \
        A##m.y = fmaf(f.x, w0.y, fmaf(f.y, w1.y, fmaf(f.z, w2.y, fmaf(f.w, w3.y, A##m.y)))); \
        A##m.z = fmaf(f.x, w0.z, fmaf(f.y, w1.z, fmaf(f.z, w2.z, fmaf(f.w, w3.z, A##m.z)))); \
        A##m.w = fmaf(f.x, w0.w, fmaf(f.y, w1.w, fmaf(f.z, w2.w, fmaf(f.w, w3.w, A##m.w)))); }
        REP16(KE_FMA)
#undef KE_FMA
    }

    // softmax over 512 per vertex: wave-reduce then 2-wave combine via LDS
#define KE_MAX(m) { \
        float lm = fmaxf(fmaxf(A##m.x, A##m.y), fmaxf(A##m.z, A##m.w)); \
        lm = fmaxf(lm, __shfl_xor(lm, 32)); \
        lm = fmaxf(lm, __shfl_xor(lm, 16)); \
        lm = fmaxf(lm, __shfl_xor(lm, 8)); \
        lm = fmaxf(lm, __shfl_xor(lm, 4)); \
        lm = fmaxf(lm, __shfl_xor(lm, 2)); \
        lm = fmaxf(lm, __shfl_xor(lm, 1)); \
        if (lane == 0) redmax[wid][m] = lm; }
    REP16(KE_MAX)
#undef KE_MAX
    __syncthreads();

#define KE_EXP(m) { \
        float gm = fmaxf(redmax[0][m], redmax[1][m]); \
        A##m.x = __expf(A##m.x - gm); \
        A##m.y = __expf(A##m.y - gm); \
        A##m.z = __expf(A##m.z - gm); \
        A##m.w = __expf(A##m.w - gm); \
        float ls = (A##m.x + A##m.y) + (A##m.z + A##m.w); \
        ls += __shfl_xor(ls, 32); \
        ls += __shfl_xor(ls, 16); \
        ls += __shfl_xor(ls, 8); \
        ls += __shfl_xor(ls, 4); \
        ls += __shfl_xor(ls, 2); \
        ls += __shfl_xor(ls, 1); \
        if (lane == 0) redsum[wid][m] = ls; }
    REP16(KE_EXP)
#undef KE_EXP
    __syncthreads();

#define KE_STORE(m) if (m < nv) { \
        float inv = 1.0f / (redsum[0][m] + redsum[1][m]); \
        *(float4*)(out + (size_t)(vbase + m) * 512 + s0) = \
            make_float4(A##m.x * inv, A##m.y * inv, A##m.z * inv, A##m.w * inv); }
    REP16(KE_STORE)
#undef KE_STORE
}

extern "C" void kernel_launch(void* const* d_in, const int* in_sizes, int n_in,
                              void* d_out, int out_size, void* d_ws, size_t ws_size,
                              hipStream_t stream) {
    (void)n_in; (void)out_size; (void)ws_size;
    const float* vp  = (const float*)d_in[0];
    const int*   nb1 = (const int*)d_in[1];
    const int*   nb2 = (const int*)d_in[2];
    const float* wv1 = (const float*)d_in[3];
    const float* bv1 = (const float*)d_in[4];
    const float* w1  = (const float*)d_in[5];
    const float* b1  = (const float*)d_in[6];
    const float* wv2 = (const float*)d_in[7];
    const float* bv2 = (const float*)d_in[8];
    const float* w2  = (const float*)d_in[9];
    const float* b2  = (const float*)d_in[10];
    const float* wfc = (const float*)d_in[11];
    const float* bfc = (const float*)d_in[12];
    float* out = (float*)d_out;
    const int V = in_sizes[0];

    float* ws = (float*)d_ws;
    size_t off = 0;
    float* h    = ws + off; off += (size_t)V;
    float* f1   = ws + off; off += (size_t)V * 32;
    float* h2   = ws + off; off += (size_t)V * 32;
    float* f2   = ws + off; off += (size_t)V * 64;
    float* wfcT = ws + off; off += 512 * 64;
    float* w2t  = ws + off; off += 3 * 32 * 64;

    k_prep<<<(512 * 64 + 64 * 32 * 3 + 255) / 256, 256, 0, stream>>>(wfc, w2, wfcT, w2t);
    kA<<<(V * 32 + 255) / 256, 256, 0, stream>>>(vp, nb1, wv1, bv1, h, V);
    kB<<<(V * 32 + 255) / 256, 256, 0, stream>>>(h, w1, b1, f1, V);
    kC<<<(V + 7) / 8, 256, 0, stream>>>(f1, nb2, wv2, bv2, h2, V);
    kD<<<(V + 7) / 8, 64, 0, stream>>>(h2, w2t, b2, f2, V);
    kE<<<(V + 15) / 16, 128, 0, stream>>>(f2, wfcT, bfc, out, V);
}